// Round 15
// baseline (164.302 us; speedup 1.0000x reference)
//
#include <hip/hip_runtime.h>
#include <math.h>

// ---------------------------------------------------------------------------
// DMoN pooling, edge-list formulation (dense adj never materialized).
//   0. zero_init: cd (packed cnt|deg)
//   1. count_convert: ONE 64-bit atomic per edge to cd[dst] (hi=count->rank,
//      lo=deg 2^-24 fixed point); sd[e]={src,dst}; x->bf16; W1,W2 hi/lo
//   2. scan_dis: rowptr scan (cd hi) + dis = rsqrt(deg+1) (cd lo)
//   3. scatter: p = rowptr[dst] + rank[e]  (NO atomics)
//   4. layer 1: (axhi,axlo) = split(aggregate(x_bf)) ; h_bf = relu(ax@W1+b1)
//   5. layer 2: (ahhi,ahlo) = split(aggregate(h_bf)) ; h2_bf = relu(ah@W2+b2)
//      aggregates: CHANNEL-SPLIT x2 -- two blocks per node, each half the
//      channels: NS edge-streams doubled (tail nodes 2x fewer serial iters),
//      2x blocks for load balance; paired blocks share col/coef in L2.
//   6. pool: s = softmax(h2_bf@Wp+bp) -> d_out ; partials cs[16]
//   7. edge_reduce: tr + wsum + ca[16] per block
//   8. finalize: parallel reduction, emit 3 scalars
// ---------------------------------------------------------------------------

#define ER_BLOCKS 2048

typedef unsigned short u16;
typedef unsigned long long u64;
typedef __attribute__((ext_vector_type(8))) short short8v;
typedef __attribute__((ext_vector_type(4))) float float4v;
typedef __attribute__((ext_vector_type(4))) unsigned short ushort4v;
typedef __attribute__((ext_vector_type(8))) unsigned short ushort8v;

#define DEG_SCALE 16777216.0f  // 2^24 fixed-point for packed deg

__device__ __forceinline__ u16 f2bf_rne(float x) {
  unsigned u = __float_as_uint(x);
  u = (u + 0x7fffu + ((u >> 16) & 1u)) >> 16;
  return (u16)u;
}
__device__ __forceinline__ float bf2f(u16 h) {
  return __uint_as_float(((unsigned)h) << 16);
}

// edge_index declared int64 in the reference, but JAX without x64 keeps int32.
__device__ __forceinline__ bool ei_is_i64(const int* __restrict__ ei) {
  return ((ei[1] | ei[3] | ei[5] | ei[7]) == 0);
}
__device__ __forceinline__ int ld_idx(const int* __restrict__ ei, int pos, bool i64) {
  return i64 ? ei[2 * pos] : ei[pos];
}

__global__ __launch_bounds__(256) void zero_init(int4* __restrict__ p, int n4) {
  int i = blockIdx.x * 256 + threadIdx.x;
  if (i < n4) p[i] = make_int4(0, 0, 0, 0);
}

// Blocks [0,eb): edge counting (packed 64-bit atomic) + sd narrowing.
// Blocks [eb,..): x->bf16, W1/W2 -> [n][k] bf16 hi/lo conversions.
__global__ __launch_bounds__(256) void count_convert(const int* __restrict__ ei,
                                                     const float* __restrict__ ew,
                                                     u64* __restrict__ cd,
                                                     int* __restrict__ rank,
                                                     int2* __restrict__ sd, int E,
                                                     const float* __restrict__ x,
                                                     u16* __restrict__ xbf, int nx4,
                                                     const float* __restrict__ W1,
                                                     u16* __restrict__ w1hi, u16* __restrict__ w1lo,
                                                     const float* __restrict__ W2,
                                                     u16* __restrict__ w2hi, u16* __restrict__ w2lo) {
  const int T1 = 256 * 128, T2 = 256 * 256;
  int eb = (E + 255) >> 8;
  int b = blockIdx.x;
  if (b < eb) {
    int e = b * 256 + threadIdx.x;
    if (e >= E) return;
    bool i64 = ei_is_i64(ei);
    int s = ld_idx(ei, e, i64);
    int d = ld_idx(ei, E + e, i64);
    float we = ew[e];
    sd[e] = make_int2(s, d);
    u64 pack = (1ULL << 32) | (u64)__float2uint_rn(we * DEG_SCALE);
    u64 old = atomicAdd(&cd[d], pack);
    rank[e] = (int)(old >> 32);
    return;
  }
  int idx = (b - eb) * 256 + threadIdx.x;
  if (idx < nx4) {
    float4 v = reinterpret_cast<const float4*>(x)[idx];
    ushort4v o = {f2bf_rne(v.x), f2bf_rne(v.y), f2bf_rne(v.z), f2bf_rne(v.w)};
    reinterpret_cast<ushort4v*>(xbf)[idx] = o;
    return;
  }
  idx -= nx4;
  if (idx < T1) {
    int n = idx >> 7, k = idx & 127;
    float v = W1[k * 256 + n];
    u16 h = f2bf_rne(v);
    w1hi[idx] = h;
    w1lo[idx] = f2bf_rne(v - bf2f(h));
    return;
  }
  idx -= T1;
  if (idx < T2) {
    int n = idx >> 8, k = idx & 255;
    float v = W2[k * 256 + n];
    u16 h = f2bf_rne(v);
    w2hi[idx] = h;
    w2lo[idx] = f2bf_rne(v - bf2f(h));
  }
}

// Single block: chunked scan (cd high words) -> rowptr; dis from cd low words.
__global__ __launch_bounds__(1024) void scan_dis(const u64* __restrict__ cd,
                                                 int* __restrict__ rowptr,
                                                 float* __restrict__ dis, int n) {
  __shared__ int sums[1024];
  int tid = threadIdx.x;
  for (int i = tid; i < n; i += 1024) {
    float degi = (float)(unsigned)(cd[i] & 0xFFFFFFFFull) * (1.0f / DEG_SCALE);
    dis[i] = 1.0f / sqrtf(degi + 1.0f);  // +1 = self-loop weight
  }
  int CH = (n + 1023) >> 10;
  int beg = tid * CH, end = min(beg + CH, n);
  int s = 0;
  for (int i = beg; i < end; ++i) s += (int)(cd[i] >> 32);
  sums[tid] = s;
  __syncthreads();
  for (int off = 1; off < 1024; off <<= 1) {
    int v = (tid >= off) ? sums[tid - off] : 0;
    __syncthreads();
    sums[tid] += v;
    __syncthreads();
  }
  int run = (tid == 0) ? 0 : sums[tid - 1];
  for (int i = beg; i < end; ++i) { rowptr[i] = run; run += (int)(cd[i] >> 32); }
  if (tid == 1023) rowptr[n] = run;
}

// Atomic-free scatter using precomputed rank and narrowed int2 indices.
__global__ __launch_bounds__(256) void scatter_edges(const int2* __restrict__ sd,
                                                     const float* __restrict__ ew,
                                                     const int* __restrict__ rowptr,
                                                     const int* __restrict__ rank,
                                                     const float* __restrict__ dis,
                                                     int* __restrict__ col,
                                                     float* __restrict__ coef, int E) {
  int e = blockIdx.x * 256 + threadIdx.x;
  if (e >= E) return;
  int2 ab = sd[e];
  int p = rowptr[ab.y] + rank[e];
  col[p] = ab.x;
  coef[p] = dis[ab.x] * ew[e] * dis[ab.y];
}

// Normalized aggregation, CHANNEL-SPLIT x2: block pair (2i, 2i+1) handles
// node i, halves of the channel range. Q halves -> NS doubles (more edge
// streams, shorter serial tail); paired blocks share col/coef via L2.
// bf16 gather, fp32 accum, LDS cross-slot reduce, hi/lo output.
template <int CH>
__global__ __launch_bounds__(256) void aggregate_pre(const u16* __restrict__ src,
                                                     const int* __restrict__ rowptr,
                                                     const int* __restrict__ col,
                                                     const float* __restrict__ coef,
                                                     const float* __restrict__ dis,
                                                     u16* __restrict__ ohi,
                                                     u16* __restrict__ olo, int N) {
  constexpr int CHS = CH / 2;   // channels this block covers (64 or 128)
  constexpr int Q = CHS / 8;    // ushort8 lanes per half-row (8 or 16)
  constexpr int NS = 256 / Q;   // concurrent edge slots (32 or 16)
  int bid = blockIdx.x;
  int i = bid >> 1;
  int co = (bid & 1) * CHS;     // channel base
  int t = threadIdx.x;
  int q = t % Q, slot = t / Q;
  int e0 = rowptr[i], e1 = rowptr[i + 1];
  float a[8] = {};
  float a2[8] = {};
  int p = e0 + slot;
  for (; p + NS < e1; p += 2 * NS) {
    int c0 = col[p];
    float w0 = coef[p];
    int c1 = col[p + NS];
    float w1 = coef[p + NS];
    ushort8v v0 = *reinterpret_cast<const ushort8v*>(&src[(size_t)c0 * CH + co + q * 8]);
    ushort8v v1 = *reinterpret_cast<const ushort8v*>(&src[(size_t)c1 * CH + co + q * 8]);
#pragma unroll
    for (int j = 0; j < 8; ++j) {
      a[j] += w0 * bf2f(v0[j]);
      a2[j] += w1 * bf2f(v1[j]);
    }
  }
  if (p < e1) {
    int c = col[p];
    float w = coef[p];
    ushort8v v = *reinterpret_cast<const ushort8v*>(&src[(size_t)c * CH + co + q * 8]);
#pragma unroll
    for (int j = 0; j < 8; ++j) a[j] += w * bf2f(v[j]);
  }
#pragma unroll
  for (int j = 0; j < 8; ++j) a[j] += a2[j];
  __shared__ float red[256][9];  // +1 pad: spread banks
#pragma unroll
  for (int j = 0; j < 8; ++j) red[t][j] = a[j];
  __syncthreads();
  if (slot == 0) {
#pragma unroll
    for (int s2 = 1; s2 < NS; ++s2)
#pragma unroll
      for (int j = 0; j < 8; ++j) a[j] += red[s2 * Q + q][j];
    float di = dis[i];
    float w0 = di * di;  // == 1/(deg+1): self-loop coefficient
    ushort8v xv = *reinterpret_cast<const ushort8v*>(&src[(size_t)i * CH + co + q * 8]);
    ushort8v hv, lv;
#pragma unroll
    for (int j = 0; j < 8; ++j) {
      a[j] += w0 * bf2f(xv[j]);
      u16 h = f2bf_rne(a[j]);
      hv[j] = h;
      lv[j] = f2bf_rne(a[j] - bf2f(h));
    }
    *reinterpret_cast<ushort8v*>(&ohi[(size_t)i * CH + co + q * 8]) = hv;
    *reinterpret_cast<ushort8v*>(&olo[(size_t)i * CH + co + q * 8]) = lv;
  }
}

// C[M,256] = relu(A@B + bias) via 3-term bf16 MFMA (A=Ahi+Alo, B=Bhi+Blo).
// Output bf16.
__global__ __launch_bounds__(256) void gemm_mfma(const u16* __restrict__ Ahi,
                                                 const u16* __restrict__ Alo,
                                                 const u16* __restrict__ Wthi,
                                                 const u16* __restrict__ Wtlo,
                                                 const float* __restrict__ bias,
                                                 u16* __restrict__ Cbf,
                                                 int M, int K) {
  __shared__ u16 As_hi[64][40], As_lo[64][40];
  __shared__ u16 Bs_hi[64][40], Bs_lo[64][40];
  int tid = threadIdx.x;
  int w = tid >> 6, l = tid & 63;
  int wm = w >> 1, wn = w & 1;
  int row0 = blockIdx.x * 64, col0 = blockIdx.y * 64;
  int srow = tid >> 2, sc = (tid & 3) * 8;
  int fr = l & 15, kg = (l >> 4) * 8;

  float4v acc[2][2];
#pragma unroll
  for (int i = 0; i < 2; ++i)
#pragma unroll
    for (int j = 0; j < 2; ++j) acc[i][j] = (float4v){0.f, 0.f, 0.f, 0.f};

  for (int k0 = 0; k0 < K; k0 += 32) {
    {
      int gr = row0 + srow;
      uint4 zero = make_uint4(0, 0, 0, 0);
      uint4 vh = zero, vl = zero;
      if (gr < M) {
        vh = *reinterpret_cast<const uint4*>(&Ahi[(size_t)gr * K + k0 + sc]);
        vl = *reinterpret_cast<const uint4*>(&Alo[(size_t)gr * K + k0 + sc]);
      }
      *reinterpret_cast<uint4*>(&As_hi[srow][sc]) = vh;
      *reinterpret_cast<uint4*>(&As_lo[srow][sc]) = vl;
      int bn = col0 + srow;
      uint4 bh = *reinterpret_cast<const uint4*>(&Wthi[(size_t)bn * K + k0 + sc]);
      uint4 bl = *reinterpret_cast<const uint4*>(&Wtlo[(size_t)bn * K + k0 + sc]);
      *reinterpret_cast<uint4*>(&Bs_hi[srow][sc]) = bh;
      *reinterpret_cast<uint4*>(&Bs_lo[srow][sc]) = bl;
    }
    __syncthreads();
    short8v ah[2], al[2], bh[2], bl[2];
#pragma unroll
    for (int i = 0; i < 2; ++i) {
      int r = wm * 32 + i * 16 + fr;
      ah[i] = *reinterpret_cast<const short8v*>(&As_hi[r][kg]);
      al[i] = *reinterpret_cast<const short8v*>(&As_lo[r][kg]);
    }
#pragma unroll
    for (int j = 0; j < 2; ++j) {
      int n = wn * 32 + j * 16 + fr;
      bh[j] = *reinterpret_cast<const short8v*>(&Bs_hi[n][kg]);
      bl[j] = *reinterpret_cast<const short8v*>(&Bs_lo[n][kg]);
    }
#pragma unroll
    for (int i = 0; i < 2; ++i)
#pragma unroll
      for (int j = 0; j < 2; ++j) {
        acc[i][j] = __builtin_amdgcn_mfma_f32_16x16x32_bf16(ah[i], bh[j], acc[i][j], 0, 0, 0);
        acc[i][j] = __builtin_amdgcn_mfma_f32_16x16x32_bf16(al[i], bh[j], acc[i][j], 0, 0, 0);
        acc[i][j] = __builtin_amdgcn_mfma_f32_16x16x32_bf16(ah[i], bl[j], acc[i][j], 0, 0, 0);
      }
    __syncthreads();
  }
#pragma unroll
  for (int j = 0; j < 2; ++j) {
    int gc = col0 + wn * 32 + j * 16 + fr;
    float bj = bias[gc];
#pragma unroll
    for (int i = 0; i < 2; ++i) {
#pragma unroll
      for (int r = 0; r < 4; ++r) {
        int gr = row0 + wm * 32 + i * 16 + (l >> 4) * 4 + r;
        if (gr < M) {
          float v = fmaxf(acc[i][j][r] + bj, 0.0f);
          Cbf[(size_t)gr * 256 + gc] = f2bf_rne(v);
        }
      }
    }
  }
}

// Pooling + softmax from bf16 h; per-block partials: cs[16] only.
__global__ __launch_bounds__(256) void pool_kernel(const u16* __restrict__ h,
                                                   const float* __restrict__ Wp,
                                                   const float* __restrict__ bp,
                                                   float* __restrict__ s_out,
                                                   float* __restrict__ pp, int N) {
  __shared__ float Wps[256 * 16];
  __shared__ float loc[16];
  int tid = threadIdx.x;
  for (int idx = tid; idx < 4096; idx += 256) Wps[idx] = Wp[idx];
  if (tid < 16) loc[tid] = 0.f;
  __syncthreads();
  int lane = tid & 63;
  int wave = tid >> 6;
  int k = lane & 15, g = lane >> 4;
  int node = blockIdx.x * 16 + wave * 4 + g;
  float acc = 0.f;
  if (node < N) {
    const ushort8v* hrow = reinterpret_cast<const ushort8v*>(h + (size_t)node * 256);
#pragma unroll 8
    for (int c8 = 0; c8 < 32; ++c8) {
      ushort8v hv = hrow[c8];
      int cb = c8 * 8;
#pragma unroll
      for (int j = 0; j < 8; ++j) acc += bf2f(hv[j]) * Wps[(cb + j) * 16 + k];
    }
    acc += bp[k];
  }
  float mx = acc;
#pragma unroll
  for (int off = 1; off < 16; off <<= 1) mx = fmaxf(mx, __shfl_xor(mx, off));
  float ex = (node < N) ? expf(acc - mx) : 0.f;
  float sm = ex;
#pragma unroll
  for (int off = 1; off < 16; off <<= 1) sm += __shfl_xor(sm, off);
  float sval = (node < N) ? ex / sm : 0.f;
  if (node < N) s_out[(size_t)node * 16 + k] = sval;
  float v = sval;
  v += __shfl_xor(v, 16);
  v += __shfl_xor(v, 32);
  if (lane < 16) atomicAdd(&loc[lane], v);
  __syncthreads();
  if (tid < 16) pp[(size_t)blockIdx.x * 16 + tid] = loc[tid];
}

// Per-edge: tr (4-lane-group dot, dedup'd), wsum (sub==0 lanes), ca[16]
// (sub-lane channel chunks). Per-block partial: [0]=tr [1]=wsum [2..17]=ca.
__global__ __launch_bounds__(256) void edge_reduce(const int2* __restrict__ sd,
                                                   const float* __restrict__ ew,
                                                   const float* __restrict__ s,
                                                   float* __restrict__ part, int E) {
  int tid = threadIdx.x;
  int le = tid >> 2, sub = tid & 3;
  int epi = gridDim.x * 64;
  float dotacc = 0.f, wacc = 0.f;
  float ca[4] = {0.f, 0.f, 0.f, 0.f};
  for (int e = blockIdx.x * 64 + le; e < E; e += epi) {
    int2 ab = sd[e];
    float w = ew[e];
    float4 av = *reinterpret_cast<const float4*>(s + (size_t)ab.x * 16 + sub * 4);
    float4 bv = *reinterpret_cast<const float4*>(s + (size_t)ab.y * 16 + sub * 4);
    float d = av.x * bv.x + av.y * bv.y + av.z * bv.z + av.w * bv.w;
    d += __shfl_xor(d, 1);
    d += __shfl_xor(d, 2);
    dotacc += w * d;               // 4 lane-copies/group; group-bit reduce dedups
    wacc += (sub == 0) ? w : 0.f;  // one copy per edge
    ca[0] += w * av.x; ca[1] += w * av.y; ca[2] += w * av.z; ca[3] += w * av.w;
  }
#pragma unroll
  for (int off = 4; off < 64; off <<= 1) dotacc += __shfl_xor(dotacc, off);
#pragma unroll
  for (int off = 1; off < 64; off <<= 1) wacc += __shfl_xor(wacc, off);
#pragma unroll
  for (int off = 4; off < 64; off <<= 1) {
#pragma unroll
    for (int j = 0; j < 4; ++j) ca[j] += __shfl_xor(ca[j], off);
  }
  __shared__ float loc[18];
  if (tid < 18) loc[tid] = 0.f;
  __syncthreads();
  if ((tid & 63) == 0) {
    atomicAdd(&loc[0], dotacc);
    atomicAdd(&loc[1], wacc);
  }
  if ((tid & 63) < 4) {  // lanes 0..3 hold sub=0..3 channel chunks
    int base = 2 + (tid & 63) * 4;
#pragma unroll
    for (int j = 0; j < 4; ++j) atomicAdd(&loc[base + j], ca[j]);
  }
  __syncthreads();
  if (tid < 18) part[(size_t)blockIdx.x * 18 + tid] = loc[tid];
}

// Parallel finalize: reduce ER_BLOCKS x 18 edge partials + pb x 16 cs partials.
__global__ __launch_bounds__(256) void finalize(const float* __restrict__ epart,
                                                const float* __restrict__ pp, int pb,
                                                float* __restrict__ out,
                                                int N, int s_elems) {
  __shared__ float credA[256];  // ca slices
  __shared__ float credB[256];  // cs slices
  __shared__ float vals[32];    // [0..15]=ca [16..31]=cs
  __shared__ float scal[2];     // [0]=tr [1]=wsum
  int tid = threadIdx.x;
  float a = 0.f, wv = 0.f;
  for (int b = tid; b < ER_BLOCKS; b += 256) {
    a  += epart[(size_t)b * 18 + 0];
    wv += epart[(size_t)b * 18 + 1];
  }
#pragma unroll
  for (int off = 1; off < 64; off <<= 1) {
    a += __shfl_xor(a, off);
    wv += __shfl_xor(wv, off);
  }
  if (tid == 0) { scal[0] = 0.f; scal[1] = 0.f; }
  __syncthreads();
  if ((tid & 63) == 0) {
    atomicAdd(&scal[0], a);
    atomicAdd(&scal[1], wv);
  }
  {
    int k = tid & 15, sl = tid >> 4;  // 16 slices
    float c = 0.f;
    for (int b = sl; b < ER_BLOCKS; b += 16) c += epart[(size_t)b * 18 + 2 + k];
    credA[tid] = c;
    float c2 = 0.f;
    for (int b = sl; b < pb; b += 16) c2 += pp[(size_t)b * 16 + k];
    credB[tid] = c2;
  }
  __syncthreads();
  if (tid < 32) {
    int kk = tid & 15;
    const float* srcp = (tid < 16) ? credA : credB;
    float c3 = 0.f;
#pragma unroll
    for (int s2 = 0; s2 < 16; ++s2) c3 += srcp[s2 * 16 + kk];
    vals[tid] = c3;
  }
  __syncthreads();
  if (tid == 0) {
    float tr = scal[0], m2 = scal[1];
    float ca2 = 0.f, cs2 = 0.f;
    for (int q = 0; q < 16; ++q) {
      ca2 += vals[q] * vals[q];
      cs2 += vals[16 + q] * vals[16 + q];
    }
    float sp = -(tr - ca2 / m2) / m2;
    float cl = sqrtf(cs2) / (float)N * 4.0f - 1.0f;
    out[s_elems + 0] = 100.f * (sp + cl);
    out[s_elems + 1] = 100.f * sp;
    out[s_elems + 2] = 100.f * cl;
  }
}

extern "C" void kernel_launch(void* const* d_in, const int* in_sizes, int n_in,
                              void* d_out, int out_size, void* d_ws, size_t ws_size,
                              hipStream_t stream) {
  const float* x  = (const float*)d_in[0];
  const int*   ei = (const int*)d_in[1];
  const float* ew = (const float*)d_in[2];
  const float* W1 = (const float*)d_in[3];
  const float* b1 = (const float*)d_in[4];
  const float* W2 = (const float*)d_in[5];
  const float* b2 = (const float*)d_in[6];
  const float* Wp = (const float*)d_in[7];
  const float* bp = (const float*)d_in[8];
  float* out = (float*)d_out;

  const int IN_C = 128, HID = 256;
  const int N = in_sizes[0] / IN_C;   // 10000
  const int E = in_sizes[2];          // 160000
  const int pool_blocks = (N + 15) / 16;

  char* p = (char*)d_ws;
  auto alloc = [&](size_t b) { char* r = p; p += (b + 255) & ~(size_t)255; return r; };
  u64*   cd      = (u64*)alloc((size_t)N * 8);    // packed cnt|deg
  char*  zero_end = p;
  u16*   xbf     = (u16*)alloc((size_t)N * IN_C * 2);
  u16*   hbf     = (u16*)alloc((size_t)N * HID * 2);
  u16*   hbf2    = (u16*)alloc((size_t)N * HID * 2);
  u16*   axhi    = (u16*)alloc((size_t)N * IN_C * 2);
  u16*   axlo    = (u16*)alloc((size_t)N * IN_C * 2);
  u16*   ahhi    = (u16*)alloc((size_t)N * HID * 2);
  u16*   ahlo    = (u16*)alloc((size_t)N * HID * 2);
  float* dis     = (float*)alloc((size_t)N * 4);
  u16*   w1hi    = (u16*)alloc((size_t)256 * 128 * 2);
  u16*   w1lo    = (u16*)alloc((size_t)256 * 128 * 2);
  u16*   w2hi    = (u16*)alloc((size_t)256 * 256 * 2);
  u16*   w2lo    = (u16*)alloc((size_t)256 * 256 * 2);
  int*   rowptr  = (int*)alloc((size_t)(N + 1) * 4);
  int*   rank    = (int*)alloc((size_t)E * 4);
  int2*  sd      = (int2*)alloc((size_t)E * 8);
  int*   col     = (int*)alloc((size_t)E * 4);
  float* coef    = (float*)alloc((size_t)E * 4);
  float* epart   = (float*)alloc((size_t)ER_BLOCKS * 18 * 4);
  float* pp      = (float*)alloc((size_t)pool_blocks * 16 * 4);
  if ((size_t)(p - (char*)d_ws) > ws_size) return;

  int zn4 = (int)((zero_end - (char*)cd) >> 4);
  zero_init<<<(zn4 + 255) / 256, 256, 0, stream>>>((int4*)cd, zn4);

  int eb = (E + 255) / 256;
  int nx4 = (N * IN_C) / 4;
  int conv_items = nx4 + 256 * 128 + 256 * 256;
  int cc_blocks = eb + (conv_items + 255) / 256;
  count_convert<<<cc_blocks, 256, 0, stream>>>(ei, ew, cd, rank, sd, E,
                                               x, xbf, nx4, W1, w1hi, w1lo,
                                               W2, w2hi, w2lo);
  scan_dis<<<1, 1024, 0, stream>>>(cd, rowptr, dis, N);
  scatter_edges<<<eb, 256, 0, stream>>>(sd, ew, rowptr, rank, dis, col, coef, E);

  dim3 gg((N + 63) / 64, HID / 64);
  aggregate_pre<128><<<2 * N, 256, 0, stream>>>(xbf, rowptr, col, coef, dis, axhi, axlo, N);
  gemm_mfma<<<gg, 256, 0, stream>>>(axhi, axlo, w1hi, w1lo, b1, hbf, N, IN_C);
  aggregate_pre<256><<<2 * N, 256, 0, stream>>>(hbf, rowptr, col, coef, dis, ahhi, ahlo, N);
  gemm_mfma<<<gg, 256, 0, stream>>>(ahhi, ahlo, w2hi, w2lo, b2, hbf2, N, HID);

  pool_kernel<<<pool_blocks, 256, 0, stream>>>(hbf2, Wp, bp, out, pp, N);
  edge_reduce<<<ER_BLOCKS, 256, 0, stream>>>(sd, ew, out, epart, E);
  finalize<<<1, 256, 0, stream>>>(epart, pp, pool_blocks, out, N, N * 16);
}

// Round 16
// 139.978 us; speedup vs baseline: 1.1738x; 1.1738x over previous
//
#include <hip/hip_runtime.h>
#include <math.h>

// ---------------------------------------------------------------------------
// DMoN pooling, edge-list formulation (dense adj never materialized).
// R12 configuration -- measured optimum (139.4 us) of this decomposition.
//   0. zero_init: cd (packed cnt|deg) / wdeg
//   1. count_convert: ONE 64-bit atomic per edge to cd[dst] (hi=count->rank,
//      lo=deg 2^-24 fixed point); + wdeg[src]; src32/dst32; x->bf16; W hi/lo
//   2. scan_dis: rowptr scan (cd hi) + dis = rsqrt(deg+1) (cd lo)
//   3. scatter: p = rowptr[dst] + rank[e]  (NO atomics)
//   4. layer 1: (axhi,axlo) = split(aggregate(x_bf)) ; h_bf = relu(ax@W1+b1)
//   5. layer 2: (ahhi,ahlo) = split(aggregate(h_bf)) ; h2_bf = relu(ah@W2+b2)
//      aggregates: block-per-node, 16/8 edge streams, LDS reduce
//   6. pool: s = softmax(h2_bf@Wp+bp) -> d_out ; partials cs/ca/wsum
//   7. edge_reduce: tr partials (2048 blocks, ~all edges in flight)
//   8. finalize: parallel reduction, emit 3 scalars
// ---------------------------------------------------------------------------

#define ER_BLOCKS 2048

typedef unsigned short u16;
typedef unsigned long long u64;
typedef __attribute__((ext_vector_type(8))) short short8v;
typedef __attribute__((ext_vector_type(4))) float float4v;
typedef __attribute__((ext_vector_type(4))) unsigned short ushort4v;
typedef __attribute__((ext_vector_type(8))) unsigned short ushort8v;

#define DEG_SCALE 16777216.0f  // 2^24 fixed-point for packed deg

__device__ __forceinline__ u16 f2bf_rne(float x) {
  unsigned u = __float_as_uint(x);
  u = (u + 0x7fffu + ((u >> 16) & 1u)) >> 16;
  return (u16)u;
}
__device__ __forceinline__ float bf2f(u16 h) {
  return __uint_as_float(((unsigned)h) << 16);
}

// edge_index declared int64 in the reference, but JAX without x64 keeps int32.
__device__ __forceinline__ bool ei_is_i64(const int* __restrict__ ei) {
  return ((ei[1] | ei[3] | ei[5] | ei[7]) == 0);
}
__device__ __forceinline__ int ld_idx(const int* __restrict__ ei, int pos, bool i64) {
  return i64 ? ei[2 * pos] : ei[pos];
}

__global__ __launch_bounds__(256) void zero_init(int4* __restrict__ p, int n4) {
  int i = blockIdx.x * 256 + threadIdx.x;
  if (i < n4) p[i] = make_int4(0, 0, 0, 0);
}

// Blocks [0,eb): edge counting (ONE packed 64-bit atomic to dst) + narrowing.
// Blocks [eb,..): x->bf16, W1/W2 -> [n][k] bf16 hi/lo conversions.
__global__ __launch_bounds__(256) void count_convert(const int* __restrict__ ei,
                                                     const float* __restrict__ ew,
                                                     u64* __restrict__ cd,
                                                     float* __restrict__ wdeg,
                                                     int* __restrict__ rank,
                                                     int* __restrict__ src32,
                                                     int* __restrict__ dst32, int E,
                                                     const float* __restrict__ x,
                                                     u16* __restrict__ xbf, int nx4,
                                                     const float* __restrict__ W1,
                                                     u16* __restrict__ w1hi, u16* __restrict__ w1lo,
                                                     const float* __restrict__ W2,
                                                     u16* __restrict__ w2hi, u16* __restrict__ w2lo) {
  const int T1 = 256 * 128, T2 = 256 * 256;
  int eb = (E + 255) >> 8;
  int b = blockIdx.x;
  if (b < eb) {
    int e = b * 256 + threadIdx.x;
    if (e >= E) return;
    bool i64 = ei_is_i64(ei);
    int s = ld_idx(ei, e, i64);
    int d = ld_idx(ei, E + e, i64);
    float we = ew[e];
    src32[e] = s;
    dst32[e] = d;
    u64 pack = (1ULL << 32) | (u64)__float2uint_rn(we * DEG_SCALE);
    u64 old = atomicAdd(&cd[d], pack);
    rank[e] = (int)(old >> 32);
    atomicAdd(&wdeg[s], we);
    return;
  }
  int idx = (b - eb) * 256 + threadIdx.x;
  if (idx < nx4) {
    float4 v = reinterpret_cast<const float4*>(x)[idx];
    ushort4v o = {f2bf_rne(v.x), f2bf_rne(v.y), f2bf_rne(v.z), f2bf_rne(v.w)};
    reinterpret_cast<ushort4v*>(xbf)[idx] = o;
    return;
  }
  idx -= nx4;
  if (idx < T1) {
    int n = idx >> 7, k = idx & 127;
    float v = W1[k * 256 + n];
    u16 h = f2bf_rne(v);
    w1hi[idx] = h;
    w1lo[idx] = f2bf_rne(v - bf2f(h));
    return;
  }
  idx -= T1;
  if (idx < T2) {
    int n = idx >> 8, k = idx & 255;
    float v = W2[k * 256 + n];
    u16 h = f2bf_rne(v);
    w2hi[idx] = h;
    w2lo[idx] = f2bf_rne(v - bf2f(h));
  }
}

// Single block: chunked scan (cd high words) -> rowptr; dis from cd low words.
__global__ __launch_bounds__(1024) void scan_dis(const u64* __restrict__ cd,
                                                 int* __restrict__ rowptr,
                                                 float* __restrict__ dis, int n) {
  __shared__ int sums[1024];
  int tid = threadIdx.x;
  for (int i = tid; i < n; i += 1024) {
    float degi = (float)(unsigned)(cd[i] & 0xFFFFFFFFull) * (1.0f / DEG_SCALE);
    dis[i] = 1.0f / sqrtf(degi + 1.0f);  // +1 = self-loop weight
  }
  int CH = (n + 1023) >> 10;
  int beg = tid * CH, end = min(beg + CH, n);
  int s = 0;
  for (int i = beg; i < end; ++i) s += (int)(cd[i] >> 32);
  sums[tid] = s;
  __syncthreads();
  for (int off = 1; off < 1024; off <<= 1) {
    int v = (tid >= off) ? sums[tid - off] : 0;
    __syncthreads();
    sums[tid] += v;
    __syncthreads();
  }
  int run = (tid == 0) ? 0 : sums[tid - 1];
  for (int i = beg; i < end; ++i) { rowptr[i] = run; run += (int)(cd[i] >> 32); }
  if (tid == 1023) rowptr[n] = run;
}

// Atomic-free scatter using precomputed rank and narrowed indices.
__global__ __launch_bounds__(256) void scatter_edges(const int* __restrict__ src32,
                                                     const int* __restrict__ dst32,
                                                     const float* __restrict__ ew,
                                                     const int* __restrict__ rowptr,
                                                     const int* __restrict__ rank,
                                                     const float* __restrict__ dis,
                                                     int* __restrict__ col,
                                                     float* __restrict__ coef, int E) {
  int e = blockIdx.x * 256 + threadIdx.x;
  if (e >= E) return;
  int s = src32[e];
  int d = dst32[e];
  int p = rowptr[d] + rank[e];
  col[p] = s;
  coef[p] = dis[s] * ew[e] * dis[d];
}

// Normalized aggregation: block-per-node, bf16 gather (16B/lane), fp32 accum,
// LDS cross-slot reduce, hi/lo output. Self-loop weight = dis[i]^2.
template <int CH>
__global__ __launch_bounds__(256) void aggregate_pre(const u16* __restrict__ src,
                                                     const int* __restrict__ rowptr,
                                                     const int* __restrict__ col,
                                                     const float* __restrict__ coef,
                                                     const float* __restrict__ dis,
                                                     u16* __restrict__ ohi,
                                                     u16* __restrict__ olo, int N) {
  constexpr int Q = CH / 8;    // ushort8 lanes per row (16 or 32)
  constexpr int NS = 256 / Q;  // concurrent edge slots (16 or 8)
  int i = blockIdx.x;
  int t = threadIdx.x;
  int q = t % Q, slot = t / Q;
  int e0 = rowptr[i], e1 = rowptr[i + 1];
  float a[8] = {};
  for (int p = e0 + slot; p < e1; p += NS) {
    int c = col[p];
    float w = coef[p];
    ushort8v v = *reinterpret_cast<const ushort8v*>(&src[(size_t)c * CH + q * 8]);
#pragma unroll
    for (int j = 0; j < 8; ++j) a[j] += w * bf2f(v[j]);
  }
  __shared__ float red[256][9];  // +1 pad: spread banks
#pragma unroll
  for (int j = 0; j < 8; ++j) red[t][j] = a[j];
  __syncthreads();
  if (slot == 0) {
#pragma unroll
    for (int s2 = 1; s2 < NS; ++s2)
#pragma unroll
      for (int j = 0; j < 8; ++j) a[j] += red[s2 * Q + q][j];
    float di = dis[i];
    float w0 = di * di;  // == 1/(deg+1): self-loop coefficient
    ushort8v xv = *reinterpret_cast<const ushort8v*>(&src[(size_t)i * CH + q * 8]);
    ushort8v hv, lv;
#pragma unroll
    for (int j = 0; j < 8; ++j) {
      a[j] += w0 * bf2f(xv[j]);
      u16 h = f2bf_rne(a[j]);
      hv[j] = h;
      lv[j] = f2bf_rne(a[j] - bf2f(h));
    }
    *reinterpret_cast<ushort8v*>(&ohi[(size_t)i * CH + q * 8]) = hv;
    *reinterpret_cast<ushort8v*>(&olo[(size_t)i * CH + q * 8]) = lv;
  }
}

// C[M,256] = relu(A@B + bias) via 3-term bf16 MFMA (A=Ahi+Alo, B=Bhi+Blo).
// Output bf16.
__global__ __launch_bounds__(256) void gemm_mfma(const u16* __restrict__ Ahi,
                                                 const u16* __restrict__ Alo,
                                                 const u16* __restrict__ Wthi,
                                                 const u16* __restrict__ Wtlo,
                                                 const float* __restrict__ bias,
                                                 u16* __restrict__ Cbf,
                                                 int M, int K) {
  __shared__ u16 As_hi[64][40], As_lo[64][40];
  __shared__ u16 Bs_hi[64][40], Bs_lo[64][40];
  int tid = threadIdx.x;
  int w = tid >> 6, l = tid & 63;
  int wm = w >> 1, wn = w & 1;
  int row0 = blockIdx.x * 64, col0 = blockIdx.y * 64;
  int srow = tid >> 2, sc = (tid & 3) * 8;
  int fr = l & 15, kg = (l >> 4) * 8;

  float4v acc[2][2];
#pragma unroll
  for (int i = 0; i < 2; ++i)
#pragma unroll
    for (int j = 0; j < 2; ++j) acc[i][j] = (float4v){0.f, 0.f, 0.f, 0.f};

  for (int k0 = 0; k0 < K; k0 += 32) {
    {
      int gr = row0 + srow;
      uint4 zero = make_uint4(0, 0, 0, 0);
      uint4 vh = zero, vl = zero;
      if (gr < M) {
        vh = *reinterpret_cast<const uint4*>(&Ahi[(size_t)gr * K + k0 + sc]);
        vl = *reinterpret_cast<const uint4*>(&Alo[(size_t)gr * K + k0 + sc]);
      }
      *reinterpret_cast<uint4*>(&As_hi[srow][sc]) = vh;
      *reinterpret_cast<uint4*>(&As_lo[srow][sc]) = vl;
      int bn = col0 + srow;
      uint4 bh = *reinterpret_cast<const uint4*>(&Wthi[(size_t)bn * K + k0 + sc]);
      uint4 bl = *reinterpret_cast<const uint4*>(&Wtlo[(size_t)bn * K + k0 + sc]);
      *reinterpret_cast<uint4*>(&Bs_hi[srow][sc]) = bh;
      *reinterpret_cast<uint4*>(&Bs_lo[srow][sc]) = bl;
    }
    __syncthreads();
    short8v ah[2], al[2], bh[2], bl[2];
#pragma unroll
    for (int i = 0; i < 2; ++i) {
      int r = wm * 32 + i * 16 + fr;
      ah[i] = *reinterpret_cast<const short8v*>(&As_hi[r][kg]);
      al[i] = *reinterpret_cast<const short8v*>(&As_lo[r][kg]);
    }
#pragma unroll
    for (int j = 0; j < 2; ++j) {
      int n = wn * 32 + j * 16 + fr;
      bh[j] = *reinterpret_cast<const short8v*>(&Bs_hi[n][kg]);
      bl[j] = *reinterpret_cast<const short8v*>(&Bs_lo[n][kg]);
    }
#pragma unroll
    for (int i = 0; i < 2; ++i)
#pragma unroll
      for (int j = 0; j < 2; ++j) {
        acc[i][j] = __builtin_amdgcn_mfma_f32_16x16x32_bf16(ah[i], bh[j], acc[i][j], 0, 0, 0);
        acc[i][j] = __builtin_amdgcn_mfma_f32_16x16x32_bf16(al[i], bh[j], acc[i][j], 0, 0, 0);
        acc[i][j] = __builtin_amdgcn_mfma_f32_16x16x32_bf16(ah[i], bl[j], acc[i][j], 0, 0, 0);
      }
    __syncthreads();
  }
#pragma unroll
  for (int j = 0; j < 2; ++j) {
    int gc = col0 + wn * 32 + j * 16 + fr;
    float bj = bias[gc];
#pragma unroll
    for (int i = 0; i < 2; ++i) {
#pragma unroll
      for (int r = 0; r < 4; ++r) {
        int gr = row0 + wm * 32 + i * 16 + (l >> 4) * 4 + r;
        if (gr < M) {
          float v = fmaxf(acc[i][j][r] + bj, 0.0f);
          Cbf[(size_t)gr * 256 + gc] = f2bf_rne(v);
        }
      }
    }
  }
}

// Pooling + softmax from bf16 h; per-block partials [0..15]=cs [16..31]=ca [32]=wsum.
__global__ __launch_bounds__(256) void pool_kernel(const u16* __restrict__ h,
                                                   const float* __restrict__ Wp,
                                                   const float* __restrict__ bp,
                                                   const float* __restrict__ wdeg,
                                                   float* __restrict__ s_out,
                                                   float* __restrict__ pp, int N) {
  __shared__ float Wps[256 * 16];
  __shared__ float loc[33];
  int tid = threadIdx.x;
  for (int idx = tid; idx < 4096; idx += 256) Wps[idx] = Wp[idx];
  if (tid < 33) loc[tid] = 0.f;
  __syncthreads();
  int lane = tid & 63;
  int wave = tid >> 6;
  int k = lane & 15, g = lane >> 4;
  int node = blockIdx.x * 16 + wave * 4 + g;
  float acc = 0.f, wd = 0.f;
  if (node < N) {
    wd = wdeg[node];
    const ushort8v* hrow = reinterpret_cast<const ushort8v*>(h + (size_t)node * 256);
#pragma unroll 8
    for (int c8 = 0; c8 < 32; ++c8) {
      ushort8v hv = hrow[c8];
      int cb = c8 * 8;
#pragma unroll
      for (int j = 0; j < 8; ++j) acc += bf2f(hv[j]) * Wps[(cb + j) * 16 + k];
    }
    acc += bp[k];
  }
  float mx = acc;
#pragma unroll
  for (int off = 1; off < 16; off <<= 1) mx = fmaxf(mx, __shfl_xor(mx, off));
  float ex = (node < N) ? expf(acc - mx) : 0.f;
  float sm = ex;
#pragma unroll
  for (int off = 1; off < 16; off <<= 1) sm += __shfl_xor(sm, off);
  float sval = (node < N) ? ex / sm : 0.f;
  if (node < N) s_out[(size_t)node * 16 + k] = sval;
  float v = sval;
  float v2 = wd * sval;
  float v3 = (k == 0) ? wd : 0.f;
  v += __shfl_xor(v, 16);  v += __shfl_xor(v, 32);
  v2 += __shfl_xor(v2, 16); v2 += __shfl_xor(v2, 32);
  v3 += __shfl_xor(v3, 16); v3 += __shfl_xor(v3, 32);
  if (lane < 16) {
    atomicAdd(&loc[lane], v);
    atomicAdd(&loc[16 + lane], v2);
  }
  if (lane == 0) atomicAdd(&loc[32], v3);
  __syncthreads();
  if (tid < 33) pp[(size_t)blockIdx.x * 33 + tid] = loc[tid];
}

// tr = SUM_e w*dot(s_src,s_dst); 4 lanes/edge; ~all edges in flight at once.
__global__ __launch_bounds__(256) void edge_reduce(const int* __restrict__ src32,
                                                   const int* __restrict__ dst32,
                                                   const float* __restrict__ ew,
                                                   const float* __restrict__ s,
                                                   float* __restrict__ part, int E) {
  int tid = threadIdx.x;
  int le = tid >> 2, sub = tid & 3;
  int epi = gridDim.x * 64;
  float acc = 0.f;
  for (int e = blockIdx.x * 64 + le; e < E; e += epi) {
    int a = src32[e];
    int b = dst32[e];
    float w = ew[e];
    float4 av = *reinterpret_cast<const float4*>(s + (size_t)a * 16 + sub * 4);
    float4 bv = *reinterpret_cast<const float4*>(s + (size_t)b * 16 + sub * 4);
    float d = av.x * bv.x + av.y * bv.y + av.z * bv.z + av.w * bv.w;
    d += __shfl_xor(d, 1);
    d += __shfl_xor(d, 2);
    acc += w * d;  // 4 lane-copies/group; xor-4+ reduce counts each group once
  }
#pragma unroll
  for (int off = 4; off < 64; off <<= 1) acc += __shfl_xor(acc, off);
  __shared__ float loc;
  if (tid == 0) loc = 0.f;
  __syncthreads();
  if ((tid & 63) == 0) atomicAdd(&loc, acc);
  __syncthreads();
  if (tid == 0) part[blockIdx.x] = loc;
}

// Parallel finalize: reduce ER_BLOCKS trace-partials + pb x 33 pool partials.
__global__ __launch_bounds__(256) void finalize(const float* __restrict__ epart,
                                                const float* __restrict__ pp, int pb,
                                                float* __restrict__ out,
                                                int N, int s_elems) {
  __shared__ float cred[256];
  __shared__ float vals[32];
  __shared__ float scal[2];  // [0]=tr, [1]=wsum
  int tid = threadIdx.x;
  float a = 0.f;
  for (int b = tid; b < ER_BLOCKS; b += 256) a += epart[b];
  float wv = 0.f;
  for (int b = tid; b < pb; b += 256) wv += pp[(size_t)b * 33 + 32];
#pragma unroll
  for (int off = 1; off < 64; off <<= 1) {
    a += __shfl_xor(a, off);
    wv += __shfl_xor(wv, off);
  }
  if (tid == 0) { scal[0] = 0.f; scal[1] = 0.f; }
  __syncthreads();
  if ((tid & 63) == 0) {
    atomicAdd(&scal[0], a);
    atomicAdd(&scal[1], wv);
  }
  {
    int k = tid & 31, sl = tid >> 5;
    float c = 0.f;
    for (int b = sl; b < pb; b += 8) c += pp[(size_t)b * 33 + k];
    cred[tid] = c;
  }
  __syncthreads();
  if (tid < 32) {
    float c = cred[tid];
#pragma unroll
    for (int sl = 1; sl < 8; ++sl) c += cred[sl * 32 + tid];
    vals[tid] = c;
  }
  __syncthreads();
  if (tid == 0) {
    float tr = scal[0], m2 = scal[1];
    float ca2 = 0.f, cs2 = 0.f;
    for (int k = 0; k < 16; ++k) {
      cs2 += vals[k] * vals[k];
      ca2 += vals[16 + k] * vals[16 + k];
    }
    float sp = -(tr - ca2 / m2) / m2;
    float cl = sqrtf(cs2) / (float)N * 4.0f - 1.0f;
    out[s_elems + 0] = 100.f * (sp + cl);
    out[s_elems + 1] = 100.f * sp;
    out[s_elems + 2] = 100.f * cl;
  }
}

extern "C" void kernel_launch(void* const* d_in, const int* in_sizes, int n_in,
                              void* d_out, int out_size, void* d_ws, size_t ws_size,
                              hipStream_t stream) {
  const float* x  = (const float*)d_in[0];
  const int*   ei = (const int*)d_in[1];
  const float* ew = (const float*)d_in[2];
  const float* W1 = (const float*)d_in[3];
  const float* b1 = (const float*)d_in[4];
  const float* W2 = (const float*)d_in[5];
  const float* b2 = (const float*)d_in[6];
  const float* Wp = (const float*)d_in[7];
  const float* bp = (const float*)d_in[8];
  float* out = (float*)d_out;

  const int IN_C = 128, HID = 256;
  const int N = in_sizes[0] / IN_C;   // 10000
  const int E = in_sizes[2];          // 160000
  const int pool_blocks = (N + 15) / 16;

  char* p = (char*)d_ws;
  auto alloc = [&](size_t b) { char* r = p; p += (b + 255) & ~(size_t)255; return r; };
  u64*   cd      = (u64*)alloc((size_t)N * 8);    // packed cnt|deg
  float* wdeg    = (float*)alloc((size_t)N * 4);
  char*  zero_end = p;
  u16*   xbf     = (u16*)alloc((size_t)N * IN_C * 2);
  u16*   hbf     = (u16*)alloc((size_t)N * HID * 2);
  u16*   hbf2    = (u16*)alloc((size_t)N * HID * 2);
  u16*   axhi    = (u16*)alloc((size_t)N * IN_C * 2);
  u16*   axlo    = (u16*)alloc((size_t)N * IN_C * 2);
  u16*   ahhi    = (u16*)alloc((size_t)N * HID * 2);
  u16*   ahlo    = (u16*)alloc((size_t)N * HID * 2);
  float* dis     = (float*)alloc((size_t)N * 4);
  u16*   w1hi    = (u16*)alloc((size_t)256 * 128 * 2);
  u16*   w1lo    = (u16*)alloc((size_t)256 * 128 * 2);
  u16*   w2hi    = (u16*)alloc((size_t)256 * 256 * 2);
  u16*   w2lo    = (u16*)alloc((size_t)256 * 256 * 2);
  int*   rowptr  = (int*)alloc((size_t)(N + 1) * 4);
  int*   rank    = (int*)alloc((size_t)E * 4);
  int*   src32   = (int*)alloc((size_t)E * 4);
  int*   dst32   = (int*)alloc((size_t)E * 4);
  int*   col     = (int*)alloc((size_t)E * 4);
  float* coef    = (float*)alloc((size_t)E * 4);
  float* epart   = (float*)alloc((size_t)ER_BLOCKS * 4);
  float* pp      = (float*)alloc((size_t)pool_blocks * 33 * 4);
  if ((size_t)(p - (char*)d_ws) > ws_size) return;

  int zn4 = (int)((zero_end - (char*)cd) >> 4);
  zero_init<<<(zn4 + 255) / 256, 256, 0, stream>>>((int4*)cd, zn4);

  int eb = (E + 255) / 256;
  int nx4 = (N * IN_C) / 4;
  int conv_items = nx4 + 256 * 128 + 256 * 256;
  int cc_blocks = eb + (conv_items + 255) / 256;
  count_convert<<<cc_blocks, 256, 0, stream>>>(ei, ew, cd, wdeg, rank,
                                               src32, dst32, E,
                                               x, xbf, nx4, W1, w1hi, w1lo,
                                               W2, w2hi, w2lo);
  scan_dis<<<1, 1024, 0, stream>>>(cd, rowptr, dis, N);
  scatter_edges<<<eb, 256, 0, stream>>>(src32, dst32, ew, rowptr, rank, dis,
                                        col, coef, E);

  dim3 gg((N + 63) / 64, HID / 64);
  aggregate_pre<128><<<N, 256, 0, stream>>>(xbf, rowptr, col, coef, dis, axhi, axlo, N);
  gemm_mfma<<<gg, 256, 0, stream>>>(axhi, axlo, w1hi, w1lo, b1, hbf, N, IN_C);
  aggregate_pre<256><<<N, 256, 0, stream>>>(hbf, rowptr, col, coef, dis, ahhi, ahlo, N);
  gemm_mfma<<<gg, 256, 0, stream>>>(ahhi, ahlo, w2hi, w2lo, b2, hbf2, N, HID);

  pool_kernel<<<pool_blocks, 256, 0, stream>>>(hbf2, Wp, bp, wdeg, out, pp, N);
  edge_reduce<<<ER_BLOCKS, 256, 0, stream>>>(src32, dst32, ew, out, epart, E);
  finalize<<<1, 256, 0, stream>>>(epart, pp, pool_blocks, out, N, N * 16);
}